// Round 3
// baseline (686.881 us; speedup 1.0000x reference)
//
#include <hip/hip_runtime.h>
#include <hip/hip_bf16.h>

// out = lambda * ||F^T F_star||_F^2,  F,F* fp32 [16384, 2048]
#define N_ROWS 16384
#define D_DIM  2048
#define SPLITK 4
#define PITCH  16416   // 16384 + 32 elems: breaks power-of-2 set/channel aliasing; rows stay 64-B aligned

typedef __attribute__((ext_vector_type(8))) short short8;        // 8 bf16 (4 VGPRs)
typedef __attribute__((ext_vector_type(4))) float f32x4;         // MFMA acc
typedef __attribute__((ext_vector_type(8))) unsigned short ushort8;
typedef __attribute__((ext_vector_type(4))) unsigned short ushort4v;

__device__ __forceinline__ unsigned short f2bf(float x) {
  __hip_bfloat16 b = __float2bfloat16(x);
  return *reinterpret_cast<unsigned short*>(&b);
}
__device__ __forceinline__ float bf2f(unsigned short u) {
  unsigned int v = ((unsigned int)u) << 16;
  return *reinterpret_cast<float*>(&v);
}

// ---------------- Pass 1: transpose + cast  fp32[N][D] -> bf16[D][PITCH] ----------------
__global__ void __launch_bounds__(256) transpose_cast(
    const float* __restrict__ F, const float* __restrict__ Fs,
    unsigned short* __restrict__ Fb, unsigned short* __restrict__ Fsb) {
  const float* src = blockIdx.z ? Fs : F;
  unsigned short* dst = blockIdx.z ? Fsb : Fb;
  __shared__ float tile[128][66];                // pad 66: read-side banks 2-way (free)
  const int k0 = blockIdx.x * 128;               // 128 k-tiles
  const int m0 = blockIdx.y * 64;                // 32 m-tiles
  const int t = threadIdx.x;

  {   // 128 rows x 64 cols fp32; per instr: 16 rows x 256 B contiguous
    const int lc = (t & 15) * 4;
#pragma unroll
    for (int p = 0; p < 8; ++p) {
      const int k = (t >> 4) + p * 16;
      const float4 v = *(const float4*)&src[(size_t)(k0 + k) * D_DIM + m0 + lc];
      tile[k][lc + 0] = v.x; tile[k][lc + 1] = v.y;
      tile[k][lc + 2] = v.z; tile[k][lc + 3] = v.w;
    }
  }
  __syncthreads();
  {   // 64 dst rows x 128 bf16 (256 B); lanes 0..15 cover one full row
    const int c = (t & 15) * 8;
#pragma unroll
    for (int p = 0; p < 4; ++p) {
      const int mm = (t >> 4) + p * 16;
      ushort8 o;
#pragma unroll
      for (int j = 0; j < 8; ++j) o[j] = f2bf(tile[c + j][mm]);
      *(ushort8*)&dst[(size_t)(m0 + mm) * PITCH + k0 + c] = o;
    }
  }
}

// ---------------- Pass 2: barrier-free MFMA GEMM, direct VGPR fragment loads ----------------
// No LDS, no __syncthreads, no vmcnt(0) drain: each lane dwordx4-loads its own
// 16-B A/B fragment slice, software-pipelined one K-step ahead so MFMAs wait
// only on loads issued a full iteration earlier. Wave = 64x64 tile, block = 2x2 waves.
__global__ void __launch_bounds__(256) gemm_direct(
    const unsigned short* __restrict__ Fb, const unsigned short* __restrict__ Fsb,
    unsigned short* __restrict__ Cpart) {
  const int tid = threadIdx.x;
  const int wave = tid >> 6, lane = tid & 63;
  const int wm = wave >> 1, wn = wave & 1;
  const int row = lane & 15;
  const int kq = (lane >> 4) * 8;
  const int z = blockIdx.z;
  const int KC = N_ROWS / SPLITK;                // 4096
  const int KITER = KC / 32;                     // 128

  const int m0 = blockIdx.y * 128 + wm * 64 + row;
  const int n0 = blockIdx.x * 128 + wn * 64 + row;
  const unsigned kb = (unsigned)(z * KC + kq);

  // element offsets (fit 32-bit: < 34M); bumped by 32 elems per K-step
  unsigned offA[4], offB[4];
#pragma unroll
  for (int i = 0; i < 4; ++i) {
    offA[i] = (unsigned)(m0 + i * 16) * PITCH + kb;
    offB[i] = (unsigned)(n0 + i * 16) * PITCH + kb;
  }

  f32x4 acc[4][4];
#pragma unroll
  for (int i = 0; i < 4; ++i)
#pragma unroll
    for (int j = 0; j < 4; ++j) acc[i][j] = 0.f;

  short8 a[4], b[4], na[4], nb[4];
#pragma unroll
  for (int i = 0; i < 4; ++i) {
    a[i] = *(const short8*)(Fb + offA[i]);
    b[i] = *(const short8*)(Fsb + offB[i]);
    offA[i] += 32; offB[i] += 32;
  }

  for (int it = 0; it < KITER - 1; ++it) {
#pragma unroll
    for (int i = 0; i < 4; ++i) {                // prefetch next K-step (distance 1)
      na[i] = *(const short8*)(Fb + offA[i]);
      nb[i] = *(const short8*)(Fsb + offB[i]);
      offA[i] += 32; offB[i] += 32;
    }
#pragma unroll
    for (int i = 0; i < 4; ++i)
#pragma unroll
      for (int j = 0; j < 4; ++j)
        acc[i][j] = __builtin_amdgcn_mfma_f32_16x16x32_bf16(a[i], b[j], acc[i][j], 0, 0, 0);
#pragma unroll
    for (int i = 0; i < 4; ++i) { a[i] = na[i]; b[i] = nb[i]; }
  }
#pragma unroll
  for (int i = 0; i < 4; ++i)
#pragma unroll
    for (int j = 0; j < 4; ++j)
      acc[i][j] = __builtin_amdgcn_mfma_f32_16x16x32_bf16(a[i], b[j], acc[i][j], 0, 0, 0);

  // Frobenius norm is layout-invariant: dump partials flat, coalesced, bf16.
  unsigned short* cp = Cpart + (size_t)z * (D_DIM * D_DIM)
                     + (size_t)(blockIdx.y * 16 + blockIdx.x) * 16384 + wave * 4096;
#pragma unroll
  for (int i = 0; i < 4; ++i)
#pragma unroll
    for (int j = 0; j < 4; ++j) {
      ushort4v o;
#pragma unroll
      for (int r = 0; r < 4; ++r) o[r] = f2bf(acc[i][j][r]);
      *(ushort4v*)&cp[(i * 4 + j) * 256 + lane * 4] = o;
    }
}

// ---------------- Pass 3: sum bf16 split partials, square, reduce ----------------
__global__ void __launch_bounds__(256) reduce_squares(
    const unsigned short* __restrict__ Cpart, const float* __restrict__ lam,
    float* __restrict__ out) {
  const int NQ = (D_DIM * D_DIM) / 8;            // ushort8 chunks per split
  const ushort8* c = (const ushort8*)Cpart;
  float s = 0.f;
  for (int idx = blockIdx.x * 256 + threadIdx.x; idx < NQ; idx += gridDim.x * 256) {
    float v[8];
#pragma unroll
    for (int j = 0; j < 8; ++j) v[j] = 0.f;
#pragma unroll
    for (int z = 0; z < SPLITK; ++z) {
      ushort8 u = c[(size_t)z * NQ + idx];
#pragma unroll
      for (int j = 0; j < 8; ++j) v[j] += bf2f(u[j]);
    }
#pragma unroll
    for (int j = 0; j < 8; ++j) s += v[j] * v[j];
  }
  for (int off = 32; off > 0; off >>= 1) s += __shfl_down(s, off, 64);
  __shared__ float red[4];
  const int wave = threadIdx.x >> 6, lane = threadIdx.x & 63;
  if (lane == 0) red[wave] = s;
  __syncthreads();
  if (threadIdx.x == 0) atomicAdd(out, (red[0] + red[1] + red[2] + red[3]) * lam[0]);
}

// ---------------- Fallback (only if ws too small): correct, slow ----------------
__global__ void __launch_bounds__(256) fallback_kernel(
    const float* __restrict__ F, const float* __restrict__ Fs,
    const float* __restrict__ lam, float* __restrict__ out) {
  __shared__ float sA[64][16], sB[64][16];
  const int d0 = blockIdx.y * 16, e0 = blockIdx.x * 16;
  const int t = threadIdx.x;
  const int td = t >> 4, te = t & 15;
  float s = 0.f;
  for (int k0 = 0; k0 < N_ROWS; k0 += 64) {
#pragma unroll
    for (int p = 0; p < 4; ++p) {
      const int k = (t >> 4) + p * 16;
      const int cc = t & 15;
      sA[k][cc] = F[(size_t)(k0 + k) * D_DIM + d0 + cc];
      sB[k][cc] = Fs[(size_t)(k0 + k) * D_DIM + e0 + cc];
    }
    __syncthreads();
#pragma unroll
    for (int kk = 0; kk < 64; ++kk) s += sA[kk][td] * sB[kk][te];
    __syncthreads();
  }
  float q = s * s;
  for (int off = 32; off > 0; off >>= 1) q += __shfl_down(q, off, 64);
  __shared__ float red[4];
  if ((t & 63) == 0) red[t >> 6] = q;
  __syncthreads();
  if (t == 0) atomicAdd(out, (red[0] + red[1] + red[2] + red[3]) * lam[0]);
}

extern "C" void kernel_launch(void* const* d_in, const int* in_sizes, int n_in,
                              void* d_out, int out_size, void* d_ws, size_t ws_size,
                              hipStream_t stream) {
  const float* F   = (const float*)d_in[0];
  const float* Fs  = (const float*)d_in[1];
  const float* lam = (const float*)d_in[2];
  float* out = (float*)d_out;
  hipMemsetAsync(d_out, 0, sizeof(float) * (size_t)out_size, stream);

  const size_t bf_bytes = (size_t)D_DIM * PITCH * 2;              // ~67.2 MB per matrix
  const size_t cpart_bytes = (size_t)SPLITK * D_DIM * D_DIM * 2;  // 32 MB (bf16 partials)
  const size_t need = 2 * bf_bytes + cpart_bytes;                 // ~166.5 MB

  if (ws_size >= need) {
    unsigned short* Fb  = (unsigned short*)d_ws;
    unsigned short* Fsb = Fb + (size_t)D_DIM * PITCH;
    unsigned short* Cpart = (unsigned short*)((char*)d_ws + 2 * bf_bytes);
    transpose_cast<<<dim3(128, 32, 2), 256, 0, stream>>>(F, Fs, Fb, Fsb);
    gemm_direct<<<dim3(16, 16, SPLITK), 256, 0, stream>>>(Fb, Fsb, Cpart);
    reduce_squares<<<dim3(1024), 256, 0, stream>>>(Cpart, lam, out);
  } else {
    fallback_kernel<<<dim3(128, 128), 256, 0, stream>>>(F, Fs, lam, out);
  }
}

// Round 4
// 508.116 us; speedup vs baseline: 1.3518x; 1.3518x over previous
//
#include <hip/hip_runtime.h>
#include <hip/hip_bf16.h>

// out = lambda * ||F^T F_star||_F^2,  F,F* fp32 [16384, 2048]
#define N_ROWS 16384
#define D_DIM  2048
#define SPLITK 4
#define NS     (N_ROWS / 32)     // 512 k-steps of 32
#define NP     (D_DIM / 128)     // 16 panels of 128 rows

// Packed operand layout (bf16): chunk(m_panel, k_step) = 8192 B contiguous at
// ushort offset (m_panel*NS + k_step)*4096. Within a chunk, subtile tt (16 rows):
// tt*512 + lane*8 + j  holds  A[m = panel*128 + tt*16 + (lane&15)]
//                              [k = step*32 + (lane>>4)*8 + j]
// == exactly the MFMA A/B fragment image, so GEMM staging is pure streaming.

typedef __attribute__((ext_vector_type(8))) short short8;        // 8 bf16 (4 VGPRs)
typedef __attribute__((ext_vector_type(4))) float f32x4;         // MFMA acc
typedef __attribute__((ext_vector_type(8))) unsigned short ushort8;
typedef __attribute__((ext_vector_type(4))) unsigned short ushort4v;

#define GPTR(p) ((const __attribute__((address_space(1))) void*)(p))
#define LPTR(p) ((__attribute__((address_space(3))) void*)(p))

__device__ __forceinline__ unsigned short f2bf(float x) {
  __hip_bfloat16 b = __float2bfloat16(x);
  return *reinterpret_cast<unsigned short*>(&b);
}
__device__ __forceinline__ float bf2f(unsigned short u) {
  unsigned int v = ((unsigned int)u) << 16;
  return *reinterpret_cast<float*>(&v);
}

// ---------- Pass 1: fp32[N][D] -> packed bf16 fragment image (seq. writes) ----------
// Block = 128 k x 128 m; writes 4 contiguous 8-KB chunks (32 KB sequential).
__global__ void __launch_bounds__(256) transpose_pack(
    const float* __restrict__ F, const float* __restrict__ Fs,
    unsigned short* __restrict__ Fb, unsigned short* __restrict__ Fsb) {
  const float* src = blockIdx.z ? Fs : F;
  unsigned short* dst = blockIdx.z ? Fsb : Fb;
  const int k0 = blockIdx.x * 128;               // 128 k-blocks
  const int mt = blockIdx.y;                     // 16 m-panels
  const int m0 = mt * 128;
  const int t = threadIdx.x;

  __shared__ unsigned short tile[128 * 136];     // tile[m][k], k-minor, stride 136
  unsigned int* tile32 = (unsigned int*)tile;

  // load: coalesced 512-B row segments; pack k-pairs into u32 LDS writes
#pragma unroll
  for (int p = 0; p < 8; ++p) {
    const int id = p * 256 + t;
    const int mg = id & 31;                      // group of 4 m
    const int kk = (id >> 5) * 2;                // even k
    const float4 r0 = *(const float4*)&src[(size_t)(k0 + kk) * D_DIM + m0 + mg * 4];
    const float4 r1 = *(const float4*)&src[(size_t)(k0 + kk + 1) * D_DIM + m0 + mg * 4];
    const float a0[4] = {r0.x, r0.y, r0.z, r0.w};
    const float a1[4] = {r1.x, r1.y, r1.z, r1.w};
#pragma unroll
    for (int mi = 0; mi < 4; ++mi) {
      const unsigned lo = f2bf(a0[mi]), hi = f2bf(a1[mi]);
      tile32[(mg * 4 + mi) * 68 + (kk >> 1)] = lo | (hi << 16);
    }
  }
  __syncthreads();

  // store: ds_read_b128 per thread, then 1024-B-contiguous-per-wave global stores
  const int w = t >> 6, lane = t & 63;
#pragma unroll
  for (int q = 0; q < 8; ++q) {
    const int ksl = q >> 1;                      // local k-step 0..3
    const int tt = (q & 1) * 4 + w;              // subtile 0..7
    const int m_l = tt * 16 + (lane & 15);
    const int k_l = ksl * 32 + (lane >> 4) * 8;
    const ushort8 v = *(const ushort8*)&tile[m_l * 136 + k_l];
    const size_t chunk = ((size_t)mt * NS + (k0 >> 5) + ksl) * 4096;
    *(ushort8*)&dst[chunk + (size_t)tt * 512 + lane * 8] = v;
  }
}

// ---------- Pass 2: MFMA GEMM on packed operands (m97 staging pattern) ----------
__global__ void __launch_bounds__(256) gemm_packed(
    const unsigned short* __restrict__ Fb, const unsigned short* __restrict__ Fsb,
    unsigned short* __restrict__ Cpart) {
  __shared__ unsigned short lds[8192];           // A: [0,4096) shorts, B: [4096,8192)
  const int tid = threadIdx.x;
  const int wave = tid >> 6, lane = tid & 63;
  const int wm = wave >> 1, wn = wave & 1;       // 2x2 waves, 64x64 each
  const int z = blockIdx.z;
  const int NSs = NS / SPLITK;                   // 128 k-steps per split

  size_t offA = ((size_t)blockIdx.y * NS + (size_t)z * NSs) * 4096 + (size_t)(2 * wave) * 512 + lane * 8;
  size_t offB = ((size_t)blockIdx.x * NS + (size_t)z * NSs) * 4096 + (size_t)(2 * wave) * 512 + lane * 8;
  unsigned short* lA = &lds[(2 * wave) * 512];
  unsigned short* lB = &lds[4096 + (2 * wave) * 512];

  f32x4 acc[4][4];
#pragma unroll
  for (int i = 0; i < 4; ++i)
#pragma unroll
    for (int j = 0; j < 4; ++j) acc[i][j] = 0.f;

  const unsigned short* lfa = &lds[(wm * 4) * 512];
  const unsigned short* lfb = &lds[4096 + (wn * 4) * 512];

  for (int it = 0; it < NSs; ++it) {
    __builtin_amdgcn_global_load_lds(GPTR(Fb + offA), LPTR(lA), 16, 0, 0);
    __builtin_amdgcn_global_load_lds(GPTR(Fb + offA + 512), LPTR(lA + 512), 16, 0, 0);
    __builtin_amdgcn_global_load_lds(GPTR(Fsb + offB), LPTR(lB), 16, 0, 0);
    __builtin_amdgcn_global_load_lds(GPTR(Fsb + offB + 512), LPTR(lB + 512), 16, 0, 0);
    offA += 4096; offB += 4096;
    __syncthreads();

    short8 a[4], b[4];
#pragma unroll
    for (int i = 0; i < 4; ++i) a[i] = *(const short8*)&lfa[i * 512 + lane * 8];
#pragma unroll
    for (int j = 0; j < 4; ++j) b[j] = *(const short8*)&lfb[j * 512 + lane * 8];
#pragma unroll
    for (int i = 0; i < 4; ++i)
#pragma unroll
      for (int j = 0; j < 4; ++j)
        acc[i][j] = __builtin_amdgcn_mfma_f32_16x16x32_bf16(a[i], b[j], acc[i][j], 0, 0, 0);
    __syncthreads();
  }

  // Frobenius norm is layout-invariant: dump partials flat, coalesced, bf16.
  unsigned short* cp = Cpart + (size_t)z * (D_DIM * D_DIM)
                     + (size_t)(blockIdx.y * 16 + blockIdx.x) * 16384 + wave * 4096;
#pragma unroll
  for (int i = 0; i < 4; ++i)
#pragma unroll
    for (int j = 0; j < 4; ++j) {
      ushort4v o;
#pragma unroll
      for (int r = 0; r < 4; ++r) o[r] = f2bf(acc[i][j][r]);
      *(ushort4v*)&cp[(i * 4 + j) * 256 + lane * 4] = o;
    }
}

// ---------- Pass 3: sum bf16 split partials, square, reduce ----------
__global__ void __launch_bounds__(256) reduce_squares(
    const unsigned short* __restrict__ Cpart, const float* __restrict__ lam,
    float* __restrict__ out) {
  const int NQ = (D_DIM * D_DIM) / 8;            // ushort8 chunks per split
  const ushort8* c = (const ushort8*)Cpart;
  float s = 0.f;
  for (int idx = blockIdx.x * 256 + threadIdx.x; idx < NQ; idx += gridDim.x * 256) {
    float v[8];
#pragma unroll
    for (int j = 0; j < 8; ++j) v[j] = 0.f;
#pragma unroll
    for (int z = 0; z < SPLITK; ++z) {
      ushort8 u = c[(size_t)z * NQ + idx];
#pragma unroll
      for (int j = 0; j < 8; ++j) v[j] += bf2f(u[j]);
    }
#pragma unroll
    for (int j = 0; j < 8; ++j) s += v[j] * v[j];
  }
  for (int off = 32; off > 0; off >>= 1) s += __shfl_down(s, off, 64);
  __shared__ float red[4];
  const int wave = threadIdx.x >> 6, lane = threadIdx.x & 63;
  if (lane == 0) red[wave] = s;
  __syncthreads();
  if (threadIdx.x == 0) atomicAdd(out, (red[0] + red[1] + red[2] + red[3]) * lam[0]);
}

// ---------- Fallback (only if ws too small): correct, slow ----------
__global__ void __launch_bounds__(256) fallback_kernel(
    const float* __restrict__ F, const float* __restrict__ Fs,
    const float* __restrict__ lam, float* __restrict__ out) {
  __shared__ float sA[64][16], sB[64][16];
  const int d0 = blockIdx.y * 16, e0 = blockIdx.x * 16;
  const int t = threadIdx.x;
  const int td = t >> 4, te = t & 15;
  float s = 0.f;
  for (int k0 = 0; k0 < N_ROWS; k0 += 64) {
#pragma unroll
    for (int p = 0; p < 4; ++p) {
      const int k = (t >> 4) + p * 16;
      const int cc = t & 15;
      sA[k][cc] = F[(size_t)(k0 + k) * D_DIM + d0 + cc];
      sB[k][cc] = Fs[(size_t)(k0 + k) * D_DIM + e0 + cc];
    }
    __syncthreads();
#pragma unroll
    for (int kk = 0; kk < 64; ++kk) s += sA[kk][td] * sB[kk][te];
    __syncthreads();
  }
  float q = s * s;
  for (int off = 32; off > 0; off >>= 1) q += __shfl_down(q, off, 64);
  __shared__ float red[4];
  if ((t & 63) == 0) red[t >> 6] = q;
  __syncthreads();
  if (t == 0) atomicAdd(out, (red[0] + red[1] + red[2] + red[3]) * lam[0]);
}

extern "C" void kernel_launch(void* const* d_in, const int* in_sizes, int n_in,
                              void* d_out, int out_size, void* d_ws, size_t ws_size,
                              hipStream_t stream) {
  const float* F   = (const float*)d_in[0];
  const float* Fs  = (const float*)d_in[1];
  const float* lam = (const float*)d_in[2];
  float* out = (float*)d_out;
  hipMemsetAsync(d_out, 0, sizeof(float) * (size_t)out_size, stream);

  const size_t bf_bytes = (size_t)NP * NS * 8192;                 // 64 MB per packed matrix
  const size_t cpart_bytes = (size_t)SPLITK * D_DIM * D_DIM * 2;  // 32 MB (bf16 partials)
  const size_t need = 2 * bf_bytes + cpart_bytes;                 // 160 MB

  if (ws_size >= need) {
    unsigned short* Fb  = (unsigned short*)d_ws;
    unsigned short* Fsb = Fb + bf_bytes / 2;
    unsigned short* Cpart = (unsigned short*)((char*)d_ws + 2 * bf_bytes);
    transpose_pack<<<dim3(128, 16, 2), 256, 0, stream>>>(F, Fs, Fb, Fsb);
    gemm_packed<<<dim3(16, 16, SPLITK), 256, 0, stream>>>(Fb, Fsb, Cpart);
    reduce_squares<<<dim3(1024), 256, 0, stream>>>(Cpart, lam, out);
  } else {
    fallback_kernel<<<dim3(128, 128), 256, 0, stream>>>(F, Fs, lam, out);
  }
}

// Round 5
// 501.871 us; speedup vs baseline: 1.3686x; 1.0124x over previous
//
#include <hip/hip_runtime.h>
#include <hip/hip_bf16.h>

// out = lambda * ||F^T F_star||_F^2,  F,F* fp32 [16384, 2048]
#define N_ROWS 16384
#define D_DIM  2048
#define SPLITK 4
#define NS     (N_ROWS / 32)     // 512 k-steps of 32
#define NP     (D_DIM / 128)     // 16 panels of 128 rows

// Packed operand layout (bf16): chunk(m_panel, k_step) = 8192 B contiguous at
// ushort offset (m_panel*NS + k_step)*4096. Within a chunk, subtile tt (16 rows):
// offset(m,k) = tt*512 + (k>>3)*128 + (m&15)*8 + (k&7)  ==  tt*512 + lane*8 + j
// for lane = (k>>3)<<4 | (m&15): exactly the MFMA A/B fragment image.

typedef __attribute__((ext_vector_type(8))) short short8;        // 8 bf16 (4 VGPRs)
typedef __attribute__((ext_vector_type(4))) float f32x4;         // MFMA acc
typedef __attribute__((ext_vector_type(8))) unsigned short ushort8;
typedef __attribute__((ext_vector_type(4))) unsigned short ushort4v;

#define GPTR(p) ((const __attribute__((address_space(1))) void*)(p))
#define LPTR(p) ((__attribute__((address_space(3))) void*)(p))

__device__ __forceinline__ unsigned short f2bf(float x) {
  __hip_bfloat16 b = __float2bfloat16(x);
  return *reinterpret_cast<unsigned short*>(&b);
}
__device__ __forceinline__ float bf2f(unsigned short u) {
  unsigned int v = ((unsigned int)u) << 16;
  return *reinterpret_cast<float*>(&v);
}

// ---------- Pass 1: fp32[N][D] -> packed bf16 fragment image, register-only ----------
// Block: 64 k-rows x 128 m (one panel), 256 threads, no LDS, no barrier.
// Lane holds an 8k x 4m micro-tile in registers; its 4 output ushort8s are a
// contiguous 64-B run of the packed image (write-combine friendly).
__global__ void __launch_bounds__(256) transpose_pack(
    const float* __restrict__ F, const float* __restrict__ Fs,
    unsigned short* __restrict__ Fb, unsigned short* __restrict__ Fsb) {
  const float* src = blockIdx.z ? Fs : F;
  unsigned short* dst = blockIdx.z ? Fsb : Fb;
  const int t = threadIdx.x;
  const int mt = blockIdx.y;                     // panel
  const int m0 = mt * 128;
  const int kb0 = blockIdx.x * 64;               // 64 k-rows per block

  const int mg   = t & 31;                       // m-group: cols m0 + mg*4 .. +3
  const int koct = (t >> 5) & 3;                 // k-octet within a 32-k chunk
  const int c    = t >> 7;                       // which of the 2 chunks
  const int krow = kb0 + c * 32 + koct * 8;

  float4 r[8];                                   // 8 k-rows x 4 m
#pragma unroll
  for (int j = 0; j < 8; ++j)
    r[j] = *(const float4*)&src[(size_t)(krow + j) * D_DIM + m0 + mg * 4];
  const float* rp = (const float*)r;             // rp[j*4 + i]

  const int ks = blockIdx.x * 2 + c;             // global k-step
  unsigned short* base = dst + ((size_t)mt * NS + ks) * 4096
                       + (size_t)(mg >> 2) * 512 + (size_t)koct * 128
                       + (size_t)(mg & 3) * 32;
#pragma unroll
  for (int i = 0; i < 4; ++i) {                  // 4 m values -> 4 contiguous 16-B stores
    ushort8 o;
#pragma unroll
    for (int j = 0; j < 8; ++j) o[j] = f2bf(rp[j * 4 + i]);
    *(ushort8*)&base[i * 8] = o;
  }
}

// ---------- Pass 2: MFMA GEMM on packed operands, BK=64 (2 chunks / barrier) ----------
__global__ void __launch_bounds__(256) gemm_packed(
    const unsigned short* __restrict__ Fb, const unsigned short* __restrict__ Fsb,
    unsigned short* __restrict__ Cpart) {
  __shared__ unsigned short lds[16384];          // A: 2 x 4096, B: 2 x 4096 (32 KB)
  const int tid = threadIdx.x;
  const int wave = tid >> 6, lane = tid & 63;
  const int wm = wave >> 1, wn = wave & 1;       // 2x2 waves, 64x64 each
  const int z = blockIdx.z;
  const int NSs = NS / SPLITK;                   // 128 k-steps per split
  const int NIT = NSs / 2;                       // 64 barriers

  size_t offA = ((size_t)blockIdx.y * NS + (size_t)z * NSs) * 4096
              + (size_t)(2 * wave) * 512 + lane * 8;
  size_t offB = ((size_t)blockIdx.x * NS + (size_t)z * NSs) * 4096
              + (size_t)(2 * wave) * 512 + lane * 8;
  unsigned short* lA = &lds[(2 * wave) * 512];
  unsigned short* lB = &lds[8192 + (2 * wave) * 512];

  f32x4 acc[4][4];
#pragma unroll
  for (int i = 0; i < 4; ++i)
#pragma unroll
    for (int j = 0; j < 4; ++j) acc[i][j] = 0.f;

  for (int it = 0; it < NIT; ++it) {
    // stage 2 consecutive chunks of A and B (each wave: its 2 subtiles x 2 steps)
    __builtin_amdgcn_global_load_lds(GPTR(Fb + offA),              LPTR(lA),              16, 0, 0);
    __builtin_amdgcn_global_load_lds(GPTR(Fb + offA + 512),        LPTR(lA + 512),        16, 0, 0);
    __builtin_amdgcn_global_load_lds(GPTR(Fb + offA + 4096),       LPTR(lA + 4096),       16, 0, 0);
    __builtin_amdgcn_global_load_lds(GPTR(Fb + offA + 4096 + 512), LPTR(lA + 4096 + 512), 16, 0, 0);
    __builtin_amdgcn_global_load_lds(GPTR(Fsb + offB),              LPTR(lB),              16, 0, 0);
    __builtin_amdgcn_global_load_lds(GPTR(Fsb + offB + 512),        LPTR(lB + 512),        16, 0, 0);
    __builtin_amdgcn_global_load_lds(GPTR(Fsb + offB + 4096),       LPTR(lB + 4096),       16, 0, 0);
    __builtin_amdgcn_global_load_lds(GPTR(Fsb + offB + 4096 + 512), LPTR(lB + 4096 + 512), 16, 0, 0);
    offA += 8192; offB += 8192;
    __syncthreads();

#pragma unroll
    for (int s = 0; s < 2; ++s) {
      short8 a[4], b[4];
#pragma unroll
      for (int i = 0; i < 4; ++i)
        a[i] = *(const short8*)&lds[s * 4096 + (wm * 4 + i) * 512 + lane * 8];
#pragma unroll
      for (int j = 0; j < 4; ++j)
        b[j] = *(const short8*)&lds[8192 + s * 4096 + (wn * 4 + j) * 512 + lane * 8];
#pragma unroll
      for (int i = 0; i < 4; ++i)
#pragma unroll
        for (int j = 0; j < 4; ++j)
          acc[i][j] = __builtin_amdgcn_mfma_f32_16x16x32_bf16(a[i], b[j], acc[i][j], 0, 0, 0);
    }
    __syncthreads();
  }

  // Frobenius norm is layout-invariant: dump partials flat, coalesced, bf16.
  unsigned short* cp = Cpart + (size_t)z * (D_DIM * D_DIM)
                     + (size_t)(blockIdx.y * 16 + blockIdx.x) * 16384 + wave * 4096;
#pragma unroll
  for (int i = 0; i < 4; ++i)
#pragma unroll
    for (int j = 0; j < 4; ++j) {
      ushort4v o;
#pragma unroll
      for (int r = 0; r < 4; ++r) o[r] = f2bf(acc[i][j][r]);
      *(ushort4v*)&cp[(i * 4 + j) * 256 + lane * 4] = o;
    }
}

// ---------- Pass 3: sum bf16 split partials, square, reduce ----------
__global__ void __launch_bounds__(256) reduce_squares(
    const unsigned short* __restrict__ Cpart, const float* __restrict__ lam,
    float* __restrict__ out) {
  const int NQ = (D_DIM * D_DIM) / 8;            // ushort8 chunks per split
  const ushort8* c = (const ushort8*)Cpart;
  float s = 0.f;
  for (int idx = blockIdx.x * 256 + threadIdx.x; idx < NQ; idx += gridDim.x * 256) {
    float v[8];
#pragma unroll
    for (int j = 0; j < 8; ++j) v[j] = 0.f;
#pragma unroll
    for (int z = 0; z < SPLITK; ++z) {
      ushort8 u = c[(size_t)z * NQ + idx];
#pragma unroll
      for (int j = 0; j < 8; ++j) v[j] += bf2f(u[j]);
    }
#pragma unroll
    for (int j = 0; j < 8; ++j) s += v[j] * v[j];
  }
  for (int off = 32; off > 0; off >>= 1) s += __shfl_down(s, off, 64);
  __shared__ float red[4];
  const int wave = threadIdx.x >> 6, lane = threadIdx.x & 63;
  if (lane == 0) red[wave] = s;
  __syncthreads();
  if (threadIdx.x == 0) atomicAdd(out, (red[0] + red[1] + red[2] + red[3]) * lam[0]);
}

// ---------- Fallback (only if ws too small): correct, slow ----------
__global__ void __launch_bounds__(256) fallback_kernel(
    const float* __restrict__ F, const float* __restrict__ Fs,
    const float* __restrict__ lam, float* __restrict__ out) {
  __shared__ float sA[64][16], sB[64][16];
  const int d0 = blockIdx.y * 16, e0 = blockIdx.x * 16;
  const int t = threadIdx.x;
  const int td = t >> 4, te = t & 15;
  float s = 0.f;
  for (int k0 = 0; k0 < N_ROWS; k0 += 64) {
#pragma unroll
    for (int p = 0; p < 4; ++p) {
      const int k = (t >> 4) + p * 16;
      const int cc = t & 15;
      sA[k][cc] = F[(size_t)(k0 + k) * D_DIM + d0 + cc];
      sB[k][cc] = Fs[(size_t)(k0 + k) * D_DIM + e0 + cc];
    }
    __syncthreads();
#pragma unroll
    for (int kk = 0; kk < 64; ++kk) s += sA[kk][td] * sB[kk][te];
    __syncthreads();
  }
  float q = s * s;
  for (int off = 32; off > 0; off >>= 1) q += __shfl_down(q, off, 64);
  __shared__ float red[4];
  if ((t & 63) == 0) red[t >> 6] = q;
  __syncthreads();
  if (t == 0) atomicAdd(out, (red[0] + red[1] + red[2] + red[3]) * lam[0]);
}

extern "C" void kernel_launch(void* const* d_in, const int* in_sizes, int n_in,
                              void* d_out, int out_size, void* d_ws, size_t ws_size,
                              hipStream_t stream) {
  const float* F   = (const float*)d_in[0];
  const float* Fs  = (const float*)d_in[1];
  const float* lam = (const float*)d_in[2];
  float* out = (float*)d_out;
  hipMemsetAsync(d_out, 0, sizeof(float) * (size_t)out_size, stream);

  const size_t bf_bytes = (size_t)NP * NS * 8192;                 // 64 MB per packed matrix
  const size_t cpart_bytes = (size_t)SPLITK * D_DIM * D_DIM * 2;  // 32 MB (bf16 partials)
  const size_t need = 2 * bf_bytes + cpart_bytes;                 // 160 MB

  if (ws_size >= need) {
    unsigned short* Fb  = (unsigned short*)d_ws;
    unsigned short* Fsb = Fb + bf_bytes / 2;
    unsigned short* Cpart = (unsigned short*)((char*)d_ws + 2 * bf_bytes);
    transpose_pack<<<dim3(N_ROWS / 64, NP, 2), 256, 0, stream>>>(F, Fs, Fb, Fsb);
    gemm_packed<<<dim3(16, 16, SPLITK), 256, 0, stream>>>(Fb, Fsb, Cpart);
    reduce_squares<<<dim3(1024), 256, 0, stream>>>(Cpart, lam, out);
  } else {
    fallback_kernel<<<dim3(128, 128), 256, 0, stream>>>(F, Fs, lam, out);
  }
}